// Round 1
// baseline (596.777 us; speedup 1.0000x reference)
//
#include <hip/hip_runtime.h>

typedef __bf16 bf16x8 __attribute__((ext_vector_type(8)));
typedef __bf16 bf16x4 __attribute__((ext_vector_type(4)));
typedef float f32x4 __attribute__((ext_vector_type(4)));

__device__ __forceinline__ f32x4 mfma16(bf16x8 a, bf16x8 b, f32x4 c) {
  return __builtin_amdgcn_mfma_f32_16x16x32_bf16(a, b, c, 0, 0, 0);
}

// ---------------- weight transpose + cast: W[k][n] (fp32) -> WT[n][k] (bf16) ----------------
__global__ __launch_bounds__(256) void prep_w_kernel(
    const float* __restrict__ Wq, const float* __restrict__ Wk,
    const float* __restrict__ Wv, const float* __restrict__ Wo,
    __bf16* __restrict__ WqT, __bf16* __restrict__ WkvT, __bf16* __restrict__ WoT) {
  __shared__ float tile[32][33];
  const int z = blockIdx.z;
  const float* W = (z == 0) ? Wq : (z == 1) ? Wk : (z == 2) ? Wv : Wo;
  __bf16* out = (z == 0) ? WqT : (z == 3) ? WoT : WkvT;
  const int rowOff = (z == 2) ? 768 : 0;
  const int tx = threadIdx.x, ty = threadIdx.y;
  const int x = blockIdx.x * 32 + tx;  // n (fast dim of W)
  const int y = blockIdx.y * 32 + ty;  // k
#pragma unroll
  for (int i = 0; i < 32; i += 8) tile[ty + i][tx] = W[(size_t)(y + i) * 768 + x];
  __syncthreads();
  const int nx = blockIdx.y * 32 + tx;  // k (fast dim of WT)
  const int ny = blockIdx.x * 32 + ty;  // n
#pragma unroll
  for (int i = 0; i < 32; i += 8)
    out[(size_t)(rowOff + ny + i) * 768 + nx] = (__bf16)tile[tx][ty + i];
}

// ---------------- LayerNorm stats: one wave per row of e ----------------
__global__ __launch_bounds__(256) void ln_stats_kernel(
    const float* __restrict__ e, float* __restrict__ mu, float* __restrict__ rs) {
  const int lane = threadIdx.x & 63;
  const int wid = threadIdx.x >> 6;
  const size_t row = (size_t)blockIdx.x * 4 + wid;
  const float* p = e + row * 768;
  float x[12];
  float sum = 0.f;
#pragma unroll
  for (int s = 0; s < 3; ++s) {
    f32x4 v = *(const f32x4*)(p + (s * 64 + lane) * 4);
#pragma unroll
    for (int q = 0; q < 4; ++q) { x[s * 4 + q] = v[q]; sum += v[q]; }
  }
#pragma unroll
  for (int d = 1; d < 64; d <<= 1) sum += __shfl_xor(sum, d);
  const float m = sum * (1.f / 768.f);
  float vs = 0.f;
#pragma unroll
  for (int q = 0; q < 12; ++q) { float d = x[q] - m; vs += d * d; }
#pragma unroll
  for (int d = 1; d < 64; d <<= 1) vs += __shfl_xor(vs, d);
  if (lane == 0) { mu[row] = m; rs[row] = rsqrtf(vs * (1.f / 768.f) + 1e-5f); }
}

// ---------------- templated 128x128 MFMA GEMM ----------------
// A [M x 768] @ W [768 x N] with WT[n][k] staged.  4 waves (2x2), each 64x64.
enum { MODE_Q = 0, MODE_KV = 1, MODE_O = 2 };

template <int MODE>
__global__ __launch_bounds__(256) void gemm_kernel(
    const float* __restrict__ Afp,   // e (Q) / h (KV) / e-residual (O)
    const __bf16* __restrict__ Abf,  // o in q-layout (O only)
    const __bf16* __restrict__ WT,   // [N][768] bf16
    const float* __restrict__ bias0, const float* __restrict__ bias1,
    const float* __restrict__ mu, const float* __restrict__ rs,
    const float* __restrict__ gamma, const float* __restrict__ beta,
    __bf16* __restrict__ dst0, __bf16* __restrict__ dst1,
    float* __restrict__ outp) {
  __shared__ __bf16 As[128][72];
  __shared__ __bf16 Bs[128][72];
  const int t = threadIdx.x;
  const int lane = t & 63, wid = t >> 6;
  const int wm = wid >> 1, wn = wid & 1;
  const int lr = lane & 15, lg = lane >> 4;
  const int rowBase = blockIdx.y * 128;
  const int colBase = blockIdx.x * 128;
  f32x4 acc[4][4] = {};
  for (int kb = 0; kb < 12; ++kb) {
    // ---- stage A tile (128 rows x 64 k), 4 elements per thread per segment ----
#pragma unroll
    for (int s = 0; s < 8; ++s) {
      const int li = (s * 256 + t) * 4;
      const int row = li >> 6, kcol = li & 63;
      const int r = rowBase + row;
      bf16x4 pk;
      if constexpr (MODE == MODE_O) {
        pk = *(const bf16x4*)(Abf + ((((size_t)(r >> 6)) * 12 + kb) << 12) + ((r & 63) << 6) + kcol);
      } else {
        f32x4 v = *(const f32x4*)(Afp + (size_t)r * 768 + kb * 64 + kcol);
        if constexpr (MODE == MODE_Q) {
          const float m = mu[r], rr = rs[r];
          f32x4 g4 = *(const f32x4*)(gamma + kb * 64 + kcol);
          f32x4 b4 = *(const f32x4*)(beta + kb * 64 + kcol);
#pragma unroll
          for (int q = 0; q < 4; ++q) v[q] = (v[q] - m) * rr * g4[q] + b4[q];
        }
#pragma unroll
        for (int q = 0; q < 4; ++q) pk[q] = (__bf16)v[q];
      }
      *(bf16x4*)&As[row][kcol] = pk;
    }
    // ---- stage B tile (128 n-rows x 64 k) from WT ----
#pragma unroll
    for (int s = 0; s < 8; ++s) {
      const int li = (s * 256 + t) * 4;
      const int n = li >> 6, k = li & 63;
      *(bf16x4*)&Bs[n][k] = *(const bf16x4*)(WT + (size_t)(colBase + n) * 768 + kb * 64 + k);
    }
    __syncthreads();
    // ---- MFMA ----
#pragma unroll
    for (int kc = 0; kc < 2; ++kc) {
      bf16x8 a[4], b[4];
#pragma unroll
      for (int it = 0; it < 4; ++it)
        a[it] = *(const bf16x8*)&As[wm * 64 + it * 16 + lr][kc * 32 + lg * 8];
#pragma unroll
      for (int jt = 0; jt < 4; ++jt)
        b[jt] = *(const bf16x8*)&Bs[wn * 64 + jt * 16 + lr][kc * 32 + lg * 8];
#pragma unroll
      for (int it = 0; it < 4; ++it)
#pragma unroll
        for (int jt = 0; jt < 4; ++jt)
          acc[it][jt] = mfma16(a[it], b[jt], acc[it][jt]);
    }
    __syncthreads();
  }
  // ---- epilogue ----
  const int roww = rowBase + wm * 64;
  const int colw = colBase + wn * 64;
#pragma unroll
  for (int it = 0; it < 4; ++it) {
#pragma unroll
    for (int jt = 0; jt < 4; ++jt) {
      const int c = colw + jt * 16 + lr;
#pragma unroll
      for (int rg = 0; rg < 4; ++rg) {
        const int r = roww + it * 16 + lg * 4 + rg;
        const float val = acc[it][jt][rg];
        if constexpr (MODE == MODE_O) {
          outp[(size_t)r * 768 + c] = val + bias0[c] + Afp[(size_t)r * 768 + c];
        } else if constexpr (MODE == MODE_Q) {
          dst0[((((size_t)(r >> 6)) * 12 + (c >> 6)) << 12) + ((r & 63) << 6) + (c & 63)] =
              (__bf16)(val + bias0[c]);
        } else {  // KV: c<768 -> k[bc][h][j][d]; else v transposed [bc][h][d][j]
          if (c < 768) {
            dst0[((((size_t)(r >> 6)) * 12 + (c >> 6)) << 12) + ((r & 63) << 6) + (c & 63)] =
                (__bf16)(val + bias0[c]);
          } else {
            const int c2 = c - 768;
            dst1[((((size_t)(r >> 6)) * 12 + (c2 >> 6)) << 12) + ((c2 & 63) << 6) + (r & 63)] =
                (__bf16)(val + bias1[c2]);
          }
        }
      }
    }
  }
}

// ---------------- attention: one wave per (b,c,n,h); i=j=d=64 ----------------
__global__ __launch_bounds__(64) void attn_kernel(
    const __bf16* __restrict__ q, const __bf16* __restrict__ k,
    const __bf16* __restrict__ v, __bf16* __restrict__ o) {
  const int gid = blockIdx.x;
  const int h = gid % 12;
  const int n = (gid / 12) & 3;
  const int bc = gid / 48;
  const __bf16* qp = q + (((size_t)(bc * 4 + n) * 12 + h) << 12);
  const __bf16* kp = k + (((size_t)bc * 12 + h) << 12);
  const __bf16* vp = v + (((size_t)bc * 12 + h) << 12);
  __bf16* op = o + (((size_t)(bc * 4 + n) * 12 + h) << 12);
  const int lane = threadIdx.x;
  const int lr = lane & 15, lg = lane >> 4;
  __shared__ __bf16 P[64][72];

  // load q,k fragments straight from global (bf16, [i/j][d] row-major, 16B per lane)
  bf16x8 qf[4][2], kf[4][2];
#pragma unroll
  for (int it = 0; it < 4; ++it)
#pragma unroll
    for (int kc = 0; kc < 2; ++kc)
      qf[it][kc] = *(const bf16x8*)(qp + (it * 16 + lr) * 64 + kc * 32 + lg * 8);
#pragma unroll
  for (int jt = 0; jt < 4; ++jt)
#pragma unroll
    for (int kc = 0; kc < 2; ++kc)
      kf[jt][kc] = *(const bf16x8*)(kp + (jt * 16 + lr) * 64 + kc * 32 + lg * 8);

  // S^T = k @ q^T : lane holds S[i = it*16+lr][j = jt*16+lg*4+rg]
  f32x4 s[4][4] = {};
#pragma unroll
  for (int kc = 0; kc < 2; ++kc)
#pragma unroll
    for (int jt = 0; jt < 4; ++jt)
#pragma unroll
      for (int it = 0; it < 4; ++it)
        s[jt][it] = mfma16(kf[jt][kc], qf[it][kc], s[jt][it]);

  // softmax over j (16 in-register values + shfl over lane^16, lane^32)
  float recip[4];
#pragma unroll
  for (int it = 0; it < 4; ++it) {
    float m = -1e30f;
#pragma unroll
    for (int jt = 0; jt < 4; ++jt)
#pragma unroll
      for (int rg = 0; rg < 4; ++rg) m = fmaxf(m, s[jt][it][rg]);
    m = fmaxf(m, __shfl_xor(m, 16));
    m = fmaxf(m, __shfl_xor(m, 32));
    float sum = 0.f;
#pragma unroll
    for (int jt = 0; jt < 4; ++jt) {
      bf16x4 pk;
#pragma unroll
      for (int rg = 0; rg < 4; ++rg) {
        float p = __expf((s[jt][it][rg] - m) * 0.125f);
        sum += p;
        pk[rg] = (__bf16)p;
      }
      *(bf16x4*)&P[it * 16 + lr][jt * 16 + lg * 4] = pk;
    }
    sum += __shfl_xor(sum, 16);
    sum += __shfl_xor(sum, 32);
    recip[it] = 1.f / sum;
  }
  __syncthreads();

  // o^T = v^T @ P^T : A-frag from vT (global, [d][j]), B-frag from P (LDS, [i][j])
  bf16x8 vf[4][2];
#pragma unroll
  for (int dt = 0; dt < 4; ++dt)
#pragma unroll
    for (int kc = 0; kc < 2; ++kc)
      vf[dt][kc] = *(const bf16x8*)(vp + (dt * 16 + lr) * 64 + kc * 32 + lg * 8);
  f32x4 oacc[4][4] = {};
#pragma unroll
  for (int kc = 0; kc < 2; ++kc) {
    bf16x8 pf[4];
#pragma unroll
    for (int it = 0; it < 4; ++it)
      pf[it] = *(const bf16x8*)&P[it * 16 + lr][kc * 32 + lg * 8];
#pragma unroll
    for (int dt = 0; dt < 4; ++dt)
#pragma unroll
      for (int it = 0; it < 4; ++it)
        oacc[dt][it] = mfma16(vf[dt][kc], pf[it], oacc[dt][it]);
  }
  // write o (same layout as q slice; in-place over q is block-local safe)
#pragma unroll
  for (int it = 0; it < 4; ++it) {
    const float rc = recip[it];
#pragma unroll
    for (int dt = 0; dt < 4; ++dt) {
      bf16x4 pk;
#pragma unroll
      for (int rg = 0; rg < 4; ++rg) pk[rg] = (__bf16)(oacc[dt][it][rg] * rc);
      *(bf16x4*)(op + (size_t)(it * 16 + lr) * 64 + dt * 16 + lg * 4) = pk;
    }
  }
}

extern "C" void kernel_launch(void* const* d_in, const int* in_sizes, int n_in,
                              void* d_out, int out_size, void* d_ws, size_t ws_size,
                              hipStream_t stream) {
  const float* e  = (const float*)d_in[0];
  const float* h  = (const float*)d_in[1];
  const float* Wq = (const float*)d_in[2];
  const float* bq = (const float*)d_in[3];
  const float* Wk = (const float*)d_in[4];
  const float* bk = (const float*)d_in[5];
  const float* Wv = (const float*)d_in[6];
  const float* bv = (const float*)d_in[7];
  const float* Wo = (const float*)d_in[8];
  const float* bo = (const float*)d_in[9];
  const float* g  = (const float*)d_in[10];
  const float* b  = (const float*)d_in[11];
  float* outp = (float*)d_out;
  char* ws = (char*)d_ws;

  __bf16* WqT  = (__bf16*)(ws);                    // 768*768*2      = 1179648
  __bf16* WkvT = (__bf16*)(ws + 1179648);          // 1536*768*2     = 2359296
  __bf16* WoT  = (__bf16*)(ws + 3538944);          // 1179648
  float*  muP  = (float*)(ws + 4718592);           // 65536*4
  float*  rsP  = (float*)(ws + 4980736);           // 65536*4
  __bf16* k_ws = (__bf16*)(ws + 5242880);          // 16384*768*2    = 25165824
  __bf16* v_ws = (__bf16*)(ws + 30408704);         // 25165824
  __bf16* q_ws = (__bf16*)(ws + 55574528);         // 65536*768*2    = 100663296 (o written in-place)

  prep_w_kernel<<<dim3(24, 24, 4), dim3(32, 8), 0, stream>>>(Wq, Wk, Wv, Wo, WqT, WkvT, WoT);
  ln_stats_kernel<<<16384, 256, 0, stream>>>(e, muP, rsP);
  gemm_kernel<MODE_Q><<<dim3(6, 512), 256, 0, stream>>>(
      e, nullptr, WqT, bq, nullptr, muP, rsP, g, b, q_ws, nullptr, nullptr);
  gemm_kernel<MODE_KV><<<dim3(12, 128), 256, 0, stream>>>(
      h, nullptr, WkvT, bk, bv, nullptr, nullptr, nullptr, nullptr, k_ws, v_ws, nullptr);
  attn_kernel<<<12288, 64, 0, stream>>>(q_ws, k_ws, v_ws, q_ws);
  gemm_kernel<MODE_O><<<dim3(6, 512), 256, 0, stream>>>(
      e, q_ws, WoT, bo, nullptr, nullptr, nullptr, nullptr, nullptr, nullptr, nullptr, outp);
}

// Round 2
// 539.227 us; speedup vs baseline: 1.1067x; 1.1067x over previous
//
#include <hip/hip_runtime.h>

typedef __bf16 bf16x8 __attribute__((ext_vector_type(8)));
typedef __bf16 bf16x4 __attribute__((ext_vector_type(4)));
typedef float f32x4 __attribute__((ext_vector_type(4)));

__device__ __forceinline__ f32x4 mfma16(bf16x8 a, bf16x8 b, f32x4 c) {
  return __builtin_amdgcn_mfma_f32_16x16x32_bf16(a, b, c, 0, 0, 0);
}

// Bijective XCD chunk swizzle (m204): hw round-robins blockIdx across 8 XCDs;
// remap so each XCD owns a CONTIGUOUS chunk of logical tile ids -> blocks that
// share an operand panel land on the same XCD's L2.
template <int NWG>
__device__ __forceinline__ int xcd_swz(int orig) {
  constexpr int NX = 8;
  constexpr int q = NWG / NX;
  constexpr int r = NWG % NX;
  const int xcd = orig % NX;
  const int pos = orig / NX;
  if constexpr (r == 0) {
    return xcd * q + pos;
  } else {
    return (xcd < r ? xcd * (q + 1) : r * (q + 1) + (xcd - r) * q) + pos;
  }
}

// ---------------- weight transpose + cast: W[k][n] (fp32) -> WT[n][k] (bf16) ----------------
__global__ __launch_bounds__(256) void prep_w_kernel(
    const float* __restrict__ Wq, const float* __restrict__ Wk,
    const float* __restrict__ Wv, const float* __restrict__ Wo,
    __bf16* __restrict__ WqT, __bf16* __restrict__ WkvT, __bf16* __restrict__ WoT) {
  __shared__ float tile[32][33];
  const int z = blockIdx.z;
  const float* W = (z == 0) ? Wq : (z == 1) ? Wk : (z == 2) ? Wv : Wo;
  __bf16* out = (z == 0) ? WqT : (z == 3) ? WoT : WkvT;
  const int rowOff = (z == 2) ? 768 : 0;
  const int tx = threadIdx.x, ty = threadIdx.y;
  const int x = blockIdx.x * 32 + tx;  // n (fast dim of W)
  const int y = blockIdx.y * 32 + ty;  // k
#pragma unroll
  for (int i = 0; i < 32; i += 8) tile[ty + i][tx] = W[(size_t)(y + i) * 768 + x];
  __syncthreads();
  const int nx = blockIdx.y * 32 + tx;  // k (fast dim of WT)
  const int ny = blockIdx.x * 32 + ty;  // n
#pragma unroll
  for (int i = 0; i < 32; i += 8)
    out[(size_t)(rowOff + ny + i) * 768 + nx] = (__bf16)tile[tx][ty + i];
}

// ---------------- LayerNorm stats: one wave per row of e ----------------
__global__ __launch_bounds__(256) void ln_stats_kernel(
    const float* __restrict__ e, float* __restrict__ mu, float* __restrict__ rs) {
  const int lane = threadIdx.x & 63;
  const int wid = threadIdx.x >> 6;
  const size_t row = (size_t)blockIdx.x * 4 + wid;
  const float* p = e + row * 768;
  float x[12];
  float sum = 0.f;
#pragma unroll
  for (int s = 0; s < 3; ++s) {
    f32x4 v = *(const f32x4*)(p + (s * 64 + lane) * 4);
#pragma unroll
    for (int q = 0; q < 4; ++q) { x[s * 4 + q] = v[q]; sum += v[q]; }
  }
#pragma unroll
  for (int d = 1; d < 64; d <<= 1) sum += __shfl_xor(sum, d);
  const float m = sum * (1.f / 768.f);
  float vs = 0.f;
#pragma unroll
  for (int q = 0; q < 12; ++q) { float d = x[q] - m; vs += d * d; }
#pragma unroll
  for (int d = 1; d < 64; d <<= 1) vs += __shfl_xor(vs, d);
  if (lane == 0) { mu[row] = m; rs[row] = rsqrtf(vs * (1.f / 768.f) + 1e-5f); }
}

// ---------------- templated 128x128 MFMA GEMM ----------------
// A [M x 768] @ W [768 x N] with WT[n][k] staged.  4 waves (2x2), each 64x64.
// 1-D grid, col-fastest logical order + XCD chunk swizzle for A-panel L2 reuse.
enum { MODE_Q = 0, MODE_KV = 1, MODE_O = 2 };

template <int MODE, int NC, int NWG>
__global__ __launch_bounds__(256) void gemm_kernel(
    const float* __restrict__ Afp,   // e (Q) / h (KV) / e-residual (O)
    const __bf16* __restrict__ Abf,  // o in q-layout (O only)
    const __bf16* __restrict__ WT,   // [N][768] bf16
    const float* __restrict__ bias0, const float* __restrict__ bias1,
    const float* __restrict__ mu, const float* __restrict__ rs,
    const float* __restrict__ gamma, const float* __restrict__ beta,
    __bf16* __restrict__ dst0, __bf16* __restrict__ dst1,
    float* __restrict__ outp) {
  __shared__ __bf16 As[128][72];
  __shared__ __bf16 Bs[128][72];
  const int wgid = xcd_swz<NWG>(blockIdx.x);
  const int rowBase = (wgid / NC) * 128;
  const int colBase = (wgid % NC) * 128;
  const int t = threadIdx.x;
  const int lane = t & 63, wid = t >> 6;
  const int wm = wid >> 1, wn = wid & 1;
  const int lr = lane & 15, lg = lane >> 4;
  f32x4 acc[4][4] = {};
  for (int kb = 0; kb < 12; ++kb) {
    // ---- stage A tile (128 rows x 64 k), 4 elements per thread per segment ----
#pragma unroll
    for (int s = 0; s < 8; ++s) {
      const int li = (s * 256 + t) * 4;
      const int row = li >> 6, kcol = li & 63;
      const int r = rowBase + row;
      bf16x4 pk;
      if constexpr (MODE == MODE_O) {
        pk = *(const bf16x4*)(Abf + ((((size_t)(r >> 6)) * 12 + kb) << 12) + ((r & 63) << 6) + kcol);
      } else {
        f32x4 v = *(const f32x4*)(Afp + (size_t)r * 768 + kb * 64 + kcol);
        if constexpr (MODE == MODE_Q) {
          const float m = mu[r], rr = rs[r];
          f32x4 g4 = *(const f32x4*)(gamma + kb * 64 + kcol);
          f32x4 b4 = *(const f32x4*)(beta + kb * 64 + kcol);
#pragma unroll
          for (int q = 0; q < 4; ++q) v[q] = (v[q] - m) * rr * g4[q] + b4[q];
        }
#pragma unroll
        for (int q = 0; q < 4; ++q) pk[q] = (__bf16)v[q];
      }
      *(bf16x4*)&As[row][kcol] = pk;
    }
    // ---- stage B tile (128 n-rows x 64 k) from WT ----
#pragma unroll
    for (int s = 0; s < 8; ++s) {
      const int li = (s * 256 + t) * 4;
      const int n = li >> 6, k = li & 63;
      *(bf16x4*)&Bs[n][k] = *(const bf16x4*)(WT + (size_t)(colBase + n) * 768 + kb * 64 + k);
    }
    __syncthreads();
    // ---- MFMA ----
#pragma unroll
    for (int kc = 0; kc < 2; ++kc) {
      bf16x8 a[4], b[4];
#pragma unroll
      for (int it = 0; it < 4; ++it)
        a[it] = *(const bf16x8*)&As[wm * 64 + it * 16 + lr][kc * 32 + lg * 8];
#pragma unroll
      for (int jt = 0; jt < 4; ++jt)
        b[jt] = *(const bf16x8*)&Bs[wn * 64 + jt * 16 + lr][kc * 32 + lg * 8];
#pragma unroll
      for (int it = 0; it < 4; ++it)
#pragma unroll
        for (int jt = 0; jt < 4; ++jt)
          acc[it][jt] = mfma16(a[it], b[jt], acc[it][jt]);
    }
    __syncthreads();
  }
  // ---- epilogue ----
  const int roww = rowBase + wm * 64;
  const int colw = colBase + wn * 64;
#pragma unroll
  for (int it = 0; it < 4; ++it) {
#pragma unroll
    for (int jt = 0; jt < 4; ++jt) {
      const int c = colw + jt * 16 + lr;
#pragma unroll
      for (int rg = 0; rg < 4; ++rg) {
        const int r = roww + it * 16 + lg * 4 + rg;
        const float val = acc[it][jt][rg];
        if constexpr (MODE == MODE_O) {
          outp[(size_t)r * 768 + c] = val + bias0[c] + Afp[(size_t)r * 768 + c];
        } else if constexpr (MODE == MODE_Q) {
          dst0[((((size_t)(r >> 6)) * 12 + (c >> 6)) << 12) + ((r & 63) << 6) + (c & 63)] =
              (__bf16)(val + bias0[c]);
        } else {  // KV: c<768 -> k[bc][h][j][d]; else v transposed [bc][h][d][j]
          if (c < 768) {
            dst0[((((size_t)(r >> 6)) * 12 + (c >> 6)) << 12) + ((r & 63) << 6) + (c & 63)] =
                (__bf16)(val + bias0[c]);
          } else {
            const int c2 = c - 768;
            dst1[((((size_t)(r >> 6)) * 12 + (c2 >> 6)) << 12) + ((c2 & 63) << 6) + (r & 63)] =
                (__bf16)(val + bias1[c2]);
          }
        }
      }
    }
  }
}

// ---------------- attention: one wave per (b,c,n,h); i=j=d=64 ----------------
// logical gid = (bc*12 + h)*4 + n : 4 consecutive blocks share one (bc,h) K/V
// slice; XCD chunk swizzle keeps them on the same XCD for L2 reuse.
__global__ __launch_bounds__(64) void attn_kernel(
    const __bf16* __restrict__ q, const __bf16* __restrict__ k,
    const __bf16* __restrict__ v, __bf16* __restrict__ o) {
  const int gid = xcd_swz<12288>(blockIdx.x);
  const int n = gid & 3;
  const int bh = gid >> 2;
  const int h = bh % 12;
  const int bc = bh / 12;
  const __bf16* qp = q + (((size_t)(bc * 4 + n) * 12 + h) << 12);
  const __bf16* kp = k + (((size_t)bc * 12 + h) << 12);
  const __bf16* vp = v + (((size_t)bc * 12 + h) << 12);
  __bf16* op = o + (((size_t)(bc * 4 + n) * 12 + h) << 12);
  const int lane = threadIdx.x;
  const int lr = lane & 15, lg = lane >> 4;
  __shared__ __bf16 P[64][72];

  // load q,k fragments straight from global (bf16, [i/j][d] row-major, 16B per lane)
  bf16x8 qf[4][2], kf[4][2];
#pragma unroll
  for (int it = 0; it < 4; ++it)
#pragma unroll
    for (int kc = 0; kc < 2; ++kc)
      qf[it][kc] = *(const bf16x8*)(qp + (it * 16 + lr) * 64 + kc * 32 + lg * 8);
#pragma unroll
  for (int jt = 0; jt < 4; ++jt)
#pragma unroll
    for (int kc = 0; kc < 2; ++kc)
      kf[jt][kc] = *(const bf16x8*)(kp + (jt * 16 + lr) * 64 + kc * 32 + lg * 8);

  // S^T = k @ q^T : lane holds S[i = it*16+lr][j = jt*16+lg*4+rg]
  f32x4 s[4][4] = {};
#pragma unroll
  for (int kc = 0; kc < 2; ++kc)
#pragma unroll
    for (int jt = 0; jt < 4; ++jt)
#pragma unroll
      for (int it = 0; it < 4; ++it)
        s[jt][it] = mfma16(kf[jt][kc], qf[it][kc], s[jt][it]);

  // softmax over j (16 in-register values + shfl over lane^16, lane^32)
  float recip[4];
#pragma unroll
  for (int it = 0; it < 4; ++it) {
    float m = -1e30f;
#pragma unroll
    for (int jt = 0; jt < 4; ++jt)
#pragma unroll
      for (int rg = 0; rg < 4; ++rg) m = fmaxf(m, s[jt][it][rg]);
    m = fmaxf(m, __shfl_xor(m, 16));
    m = fmaxf(m, __shfl_xor(m, 32));
    float sum = 0.f;
#pragma unroll
    for (int jt = 0; jt < 4; ++jt) {
      bf16x4 pk;
#pragma unroll
      for (int rg = 0; rg < 4; ++rg) {
        float p = __expf((s[jt][it][rg] - m) * 0.125f);
        sum += p;
        pk[rg] = (__bf16)p;
      }
      *(bf16x4*)&P[it * 16 + lr][jt * 16 + lg * 4] = pk;
    }
    sum += __shfl_xor(sum, 16);
    sum += __shfl_xor(sum, 32);
    recip[it] = 1.f / sum;
  }
  __syncthreads();

  // o^T = v^T @ P^T : A-frag from vT (global, [d][j]), B-frag from P (LDS, [i][j])
  bf16x8 vf[4][2];
#pragma unroll
  for (int dt = 0; dt < 4; ++dt)
#pragma unroll
    for (int kc = 0; kc < 2; ++kc)
      vf[dt][kc] = *(const bf16x8*)(vp + (dt * 16 + lr) * 64 + kc * 32 + lg * 8);
  f32x4 oacc[4][4] = {};
#pragma unroll
  for (int kc = 0; kc < 2; ++kc) {
    bf16x8 pf[4];
#pragma unroll
    for (int it = 0; it < 4; ++it)
      pf[it] = *(const bf16x8*)&P[it * 16 + lr][kc * 32 + lg * 8];
#pragma unroll
    for (int dt = 0; dt < 4; ++dt)
#pragma unroll
      for (int it = 0; it < 4; ++it)
        oacc[dt][it] = mfma16(vf[dt][kc], pf[it], oacc[dt][it]);
  }
  // write o (same layout as q slice; in-place over q is block-local safe)
#pragma unroll
  for (int it = 0; it < 4; ++it) {
    const float rc = recip[it];
#pragma unroll
    for (int dt = 0; dt < 4; ++dt) {
      bf16x4 pk;
#pragma unroll
      for (int rg = 0; rg < 4; ++rg) pk[rg] = (__bf16)(oacc[dt][it][rg] * rc);
      *(bf16x4*)(op + (size_t)(it * 16 + lr) * 64 + dt * 16 + lg * 4) = pk;
    }
  }
}

extern "C" void kernel_launch(void* const* d_in, const int* in_sizes, int n_in,
                              void* d_out, int out_size, void* d_ws, size_t ws_size,
                              hipStream_t stream) {
  const float* e  = (const float*)d_in[0];
  const float* h  = (const float*)d_in[1];
  const float* Wq = (const float*)d_in[2];
  const float* bq = (const float*)d_in[3];
  const float* Wk = (const float*)d_in[4];
  const float* bk = (const float*)d_in[5];
  const float* Wv = (const float*)d_in[6];
  const float* bv = (const float*)d_in[7];
  const float* Wo = (const float*)d_in[8];
  const float* bo = (const float*)d_in[9];
  const float* g  = (const float*)d_in[10];
  const float* b  = (const float*)d_in[11];
  float* outp = (float*)d_out;
  char* ws = (char*)d_ws;

  __bf16* WqT  = (__bf16*)(ws);                    // 768*768*2      = 1179648
  __bf16* WkvT = (__bf16*)(ws + 1179648);          // 1536*768*2     = 2359296
  __bf16* WoT  = (__bf16*)(ws + 3538944);          // 1179648
  float*  muP  = (float*)(ws + 4718592);           // 65536*4
  float*  rsP  = (float*)(ws + 4980736);           // 65536*4
  __bf16* k_ws = (__bf16*)(ws + 5242880);          // 16384*768*2    = 25165824
  __bf16* v_ws = (__bf16*)(ws + 30408704);         // 25165824
  __bf16* q_ws = (__bf16*)(ws + 55574528);         // 65536*768*2    = 100663296 (o written in-place)

  prep_w_kernel<<<dim3(24, 24, 4), dim3(32, 8), 0, stream>>>(Wq, Wk, Wv, Wo, WqT, WkvT, WoT);
  ln_stats_kernel<<<16384, 256, 0, stream>>>(e, muP, rsP);
  gemm_kernel<MODE_Q, 6, 3072><<<3072, 256, 0, stream>>>(
      e, nullptr, WqT, bq, nullptr, muP, rsP, g, b, q_ws, nullptr, nullptr);
  gemm_kernel<MODE_KV, 12, 1536><<<1536, 256, 0, stream>>>(
      h, nullptr, WkvT, bk, bv, nullptr, nullptr, nullptr, nullptr, k_ws, v_ws, nullptr);
  attn_kernel<<<12288, 64, 0, stream>>>(q_ws, k_ws, v_ws, q_ws);
  gemm_kernel<MODE_O, 6, 3072><<<3072, 256, 0, stream>>>(
      e, q_ws, WoT, bo, nullptr, nullptr, nullptr, nullptr, nullptr, nullptr, nullptr, outp);
}